// Round 2
// baseline (432.867 us; speedup 1.0000x reference)
//
#include <hip/hip_runtime.h>

typedef unsigned short u16;
typedef unsigned int u32;
typedef __attribute__((ext_vector_type(8))) short bf16x8;
typedef __attribute__((ext_vector_type(4))) float f32x4;
typedef __attribute__((ext_vector_type(8))) u16 u16x8;

#define DEV __device__ __forceinline__

DEV u16 f2bf(float f) {
  u32 x = __float_as_uint(f);
  return (u16)((x + 0x7fffu + ((x >> 16) & 1u)) >> 16);  // RNE
}

// Problem dims: B=8 S=512 H=768 E=8 F=3072 K=2. All I/O fp32; internal bf16 MFMA.

// ---------- convert hidden fp32->bf16 + accumulate per-(b,h) pooled sums ----------
// grid (16 s-chunks, 8 b) x 256. pooled[8][768] must be pre-zeroed (memsetAsync).
__global__ void convert_pool_kernel(const float* __restrict__ hidden, u16* __restrict__ hbf,
                                    float* __restrict__ pooled) {
  __shared__ float lp[768];
  const int b = blockIdx.y, chunk = blockIdx.x, tid = threadIdx.x;
  for (int h = tid; h < 768; h += 256) lp[h] = 0.f;
  __syncthreads();
  const size_t base = (size_t)b * 512 * 768 + (size_t)chunk * 32 * 768;
#pragma unroll
  for (int i = 0; i < 24; ++i) {
    const int idx = i * 256 + tid;              // float4 index within 32x768 chunk
    const float4 v = *(const float4*)(hidden + base + (size_t)idx * 4);
    u16x8 dummy;
    u16* d = hbf + base + (size_t)idx * 4;
    d[0] = f2bf(v.x); d[1] = f2bf(v.y); d[2] = f2bf(v.z); d[3] = f2bf(v.w);
    const int h = (idx % 192) * 4;              // 768/4 = 192 float4 per row
    atomicAdd(&lp[h + 0], v.x); atomicAdd(&lp[h + 1], v.y);
    atomicAdd(&lp[h + 2], v.z); atomicAdd(&lp[h + 3], v.w);
    (void)dummy;
  }
  __syncthreads();
  for (int h = tid; h < 768; h += 256) atomicAdd(&pooled[b * 768 + h], lp[h]);
}

// ---------- router finalize: logits = pooled@Wg/512, softmax, top2 ----------
__global__ void router_final_kernel(const float* __restrict__ pooled, const float* __restrict__ Wg,
                                    float* __restrict__ logits_out, int* __restrict__ sel,
                                    float* __restrict__ wsel) {
  __shared__ float l8[64];
  const int tid = threadIdx.x;
  const int b = tid >> 5, r = tid & 31, e = r >> 2, q = r & 3;
  float p = 0.f;
  for (int h = q * 192; h < q * 192 + 192; ++h) p += pooled[b * 768 + h] * Wg[h * 8 + e];
  p += __shfl_xor(p, 1);
  p += __shfl_xor(p, 2);
  if (q == 0) {
    const float lg = p * (1.f / 512.f);
    l8[b * 8 + e] = lg;
    logits_out[b * 8 + e] = lg;
  }
  __syncthreads();
  if (tid < 8) {
    const int bb = tid;
    float mx = -1e30f;
    for (int i = 0; i < 8; ++i) mx = fmaxf(mx, l8[bb * 8 + i]);
    float w[8], ssum = 0.f;
    for (int i = 0; i < 8; ++i) { w[i] = __expf(l8[bb * 8 + i] - mx); ssum += w[i]; }
    for (int i = 0; i < 8; ++i) w[i] /= ssum;
    int i0 = 0;
    for (int i = 1; i < 8; ++i) if (w[i] > w[i0]) i0 = i;   // first-occurrence ties (jax top_k)
    int i1 = (i0 == 0) ? 1 : 0;
    for (int i = 0; i < 8; ++i) if (i != i0 && w[i] > w[i1]) i1 = i;
    sel[bb * 2 + 0] = i0; sel[bb * 2 + 1] = i1;
    wsel[bb * 2 + 0] = w[i0]; wsel[bb * 2 + 1] = w[i1];
  }
}

// ---------- 64x64 tiled transpose, fp32 src -> bf16 dst ----------
__global__ void transpose_kernel(const float* __restrict__ src, u16* __restrict__ dst,
                                 int R, int C) {
  __shared__ u16 tile[64][72];  // 144B row stride: 16B-aligned, breaks bank stride
  const int e = blockIdx.z;
  src += (size_t)e * (size_t)R * C;
  dst += (size_t)e * (size_t)R * C;
  const int r0 = blockIdx.y * 64, c0 = blockIdx.x * 64;
  const int tid = threadIdx.x;
#pragma unroll
  for (int i = 0; i < 4; ++i) {
    const int ch = i * 256 + tid;              // 0..1023 float4-chunks
    const int row = ch >> 4, c4 = (ch & 15) * 4;
    const float4 v = *(const float4*)(src + (size_t)(r0 + row) * C + c0 + c4);
    tile[row][c4 + 0] = f2bf(v.x); tile[row][c4 + 1] = f2bf(v.y);
    tile[row][c4 + 2] = f2bf(v.z); tile[row][c4 + 3] = f2bf(v.w);
  }
  __syncthreads();
#pragma unroll
  for (int i = 0; i < 2; ++i) {
    const int ch = i * 256 + tid;
    const int drow = ch >> 3, r8 = (ch & 7) * 8;
    u16x8 v;
#pragma unroll
    for (int j = 0; j < 8; ++j) v[j] = tile[r8 + j][drow];
    *(u16x8*)(dst + (size_t)(c0 + drow) * R + r0 + r8) = v;
  }
}

// ---------- GEMM core (m97 structure): 128x128 tile, BK=64, 16x16x32 bf16 ----------
DEV void stage_tile(const u16* __restrict__ gbase, int ld, int row0, int k0,
                    u16* lds, int tid) {
  const int crow = tid >> 3;          // 0..31
  const int ccol = (tid & 7) * 8;     // k offset (elems)
  const int wbase = tid & ~63;        // wave-uniform chunk base
#pragma unroll
  for (int i = 0; i < 4; ++i) {
    const u16* g = gbase + (size_t)(row0 + i * 32 + crow) * ld + k0 + ccol;
    u16* l = lds + (size_t)(i * 256 + wbase) * 8;  // HW adds lane*16B
    __builtin_amdgcn_global_load_lds((const __attribute__((address_space(1))) void*)g,
                                     (__attribute__((address_space(3))) void*)l, 16, 0, 0);
  }
}

DEV void mfma_step(const u16* As, const u16* Bs, int wm, int wn, int mi, int kq,
                   f32x4 acc[4][4]) {
#pragma unroll
  for (int s2 = 0; s2 < 64; s2 += 32) {
    bf16x8 af[4], bfr[4];
#pragma unroll
    for (int mt = 0; mt < 4; ++mt)
      af[mt] = *(const bf16x8*)(As + (wm + mt * 16 + mi) * 64 + s2 + kq * 8);
#pragma unroll
    for (int nt = 0; nt < 4; ++nt)
      bfr[nt] = *(const bf16x8*)(Bs + (wn + nt * 16 + mi) * 64 + s2 + kq * 8);
#pragma unroll
    for (int mt = 0; mt < 4; ++mt)
#pragma unroll
      for (int nt = 0; nt < 4; ++nt)
        acc[mt][nt] = __builtin_amdgcn_mfma_f32_16x16x32_bf16(af[mt], bfr[nt], acc[mt][nt], 0, 0, 0);
  }
}

// ---------- GEMM1: hbuf = wgt * gelu(hbf @ W1[e] + b1[e]), bf16 out ----------
__global__ void gemm1_kernel(const u16* __restrict__ hbf, const u16* __restrict__ w1t,
                             const float* __restrict__ b1, u16* __restrict__ hbuf,
                             const int* __restrict__ sel, const float* __restrict__ wsel) {
  __shared__ __align__(16) u16 As[128 * 64];
  __shared__ __align__(16) u16 Bs[128 * 64];
  const int p = blockIdx.z;
  const int b = p >> 1;
  const int e = sel[p];
  const float wgt = wsel[p];
  const u16* A = hbf + (size_t)b * 512 * 768;
  const u16* Bt = w1t + (size_t)e * 3072 * 768;
  const int m0 = blockIdx.y * 128, n0 = blockIdx.x * 128;
  const int tid = threadIdx.x, lane = tid & 63;
  const int wv = tid >> 6;
  const int wm = (wv >> 1) * 64, wn = (wv & 1) * 64;
  const int mi = lane & 15, kq = lane >> 4;

  f32x4 acc[4][4] = {};
  for (int k0 = 0; k0 < 768; k0 += 64) {
    __syncthreads();
    stage_tile(A, 768, m0, k0, As, tid);
    stage_tile(Bt, 768, n0, k0, Bs, tid);
    __syncthreads();  // drains vmcnt before any wave reads LDS
    mfma_step(As, Bs, wm, wn, mi, kq, acc);
  }

  const float* b1e = b1 + e * 3072;
  u16* C = hbuf + (size_t)p * 512 * 3072;
#pragma unroll
  for (int nt = 0; nt < 4; ++nt) {
    const int col = n0 + wn + nt * 16 + mi;
    const float bias = b1e[col];
#pragma unroll
    for (int mt = 0; mt < 4; ++mt) {
#pragma unroll
      for (int r = 0; r < 4; ++r) {
        const int row = m0 + wm + mt * 16 + kq * 4 + r;  // C/D: col=lane&15, row=quad*4+reg
        const float x = acc[mt][nt][r] + bias;
        const float g = 0.5f * x * (1.f + erff(x * 0.70710678118654752f));  // exact GELU
        C[(size_t)row * 3072 + col] = f2bf(wgt * g);
      }
    }
  }
}

// ---------- GEMM2: out[b] = sum_k hbuf_k @ W2[e_k] + sum_k w_k*b2[e_k], fp32 out ----------
__global__ void gemm2_kernel(const u16* __restrict__ hbuf, const u16* __restrict__ w2t,
                             const float* __restrict__ b2, float* __restrict__ out,
                             const int* __restrict__ sel, const float* __restrict__ wsel) {
  __shared__ __align__(16) u16 As[128 * 64];
  __shared__ __align__(16) u16 Bs[128 * 64];
  const int b = blockIdx.z;
  const int e0 = sel[b * 2 + 0], e1 = sel[b * 2 + 1];
  const float w0 = wsel[b * 2 + 0], w1 = wsel[b * 2 + 1];
  const u16* A0 = hbuf + (size_t)(b * 2) * 512 * 3072;
  const u16* B0 = w2t + (size_t)e0 * 768 * 3072;
  const u16* B1 = w2t + (size_t)e1 * 768 * 3072;
  const int m0 = blockIdx.y * 128, n0 = blockIdx.x * 128;
  const int tid = threadIdx.x, lane = tid & 63;
  const int wv = tid >> 6;
  const int wm = (wv >> 1) * 64, wn = (wv & 1) * 64;
  const int mi = lane & 15, kq = lane >> 4;

  f32x4 acc[4][4] = {};
  for (int t = 0; t < 96; ++t) {
    const int second = (t >= 48) ? 1 : 0;
    const u16* A = A0 + (size_t)second * 512 * 3072;
    const u16* Bt = second ? B1 : B0;
    const int k0 = (t - second * 48) * 64;
    __syncthreads();
    stage_tile(A, 3072, m0, k0, As, tid);
    stage_tile(Bt, 3072, n0, k0, Bs, tid);
    __syncthreads();
    mfma_step(As, Bs, wm, wn, mi, kq, acc);
  }

  const float* b2e0 = b2 + e0 * 768;
  const float* b2e1 = b2 + e1 * 768;
  float* C = out + (size_t)b * 512 * 768;
#pragma unroll
  for (int nt = 0; nt < 4; ++nt) {
    const int col = n0 + wn + nt * 16 + mi;
    const float bias = w0 * b2e0[col] + w1 * b2e1[col];
#pragma unroll
    for (int mt = 0; mt < 4; ++mt) {
#pragma unroll
      for (int r = 0; r < 4; ++r) {
        const int row = m0 + wm + mt * 16 + kq * 4 + r;
        C[(size_t)row * 768 + col] = acc[mt][nt][r] + bias;
      }
    }
  }
}

extern "C" void kernel_launch(void* const* d_in, const int* in_sizes, int n_in,
                              void* d_out, int out_size, void* d_ws, size_t ws_size,
                              hipStream_t stream) {
  const float* hidden = (const float*)d_in[0];  // [8,512,768] fp32
  const float* Wg     = (const float*)d_in[1];  // [768,8]
  const float* W1     = (const float*)d_in[2];  // [8,768,3072]
  const float* b1     = (const float*)d_in[3];  // [8,3072]
  const float* W2     = (const float*)d_in[4];  // [8,3072,768]
  const float* b2     = (const float*)d_in[5];  // [8,768]
  float* out = (float*)d_out;                   // [8,512,768] ++ logits [8,8], fp32

  // workspace layout (~94.4 MB): w2t reuses w1t's slot after gemm1
  char* ws = (char*)d_ws;
  int*   sel    = (int*)ws;                     // [16]
  float* wsel   = (float*)(ws + 64);            // [16]
  float* pooled = (float*)(ws + 128);           // [8][768] fp32 (zeroed below)
  u16* hbf  = (u16*)(ws + 32768);               // [8][512][768] bf16
  u16* wT   = hbf + (size_t)8 * 512 * 768;      // [8][3072][768] bf16 (w1t, then w2t)
  u16* hbuf = wT + (size_t)8 * 3072 * 768;      // [16][512][3072] bf16

  float* logits_out = out + (size_t)8 * 512 * 768;

  hipMemsetAsync(ws, 0, 32768, stream);  // zero sel/wsel/pooled
  convert_pool_kernel<<<dim3(16, 8), 256, 0, stream>>>(hidden, hbf, pooled);
  router_final_kernel<<<1, 256, 0, stream>>>(pooled, Wg, logits_out, sel, wsel);
  transpose_kernel<<<dim3(48, 12, 8), 256, 0, stream>>>(W1, wT, 768, 3072);   // [H,F]->[F,H]
  gemm1_kernel<<<dim3(24, 4, 16), 256, 0, stream>>>(hbf, wT, b1, hbuf, sel, wsel);
  transpose_kernel<<<dim3(12, 48, 8), 256, 0, stream>>>(W2, wT, 3072, 768);   // [F,H]->[H,F]
  gemm2_kernel<<<dim3(6, 4, 8), 256, 0, stream>>>(hbuf, wT, b2, out, sel, wsel);
}

// Round 3
// 399.366 us; speedup vs baseline: 1.0839x; 1.0839x over previous
//
#include <hip/hip_runtime.h>

typedef unsigned short u16;
typedef unsigned int u32;
typedef __attribute__((ext_vector_type(8))) short bf16x8;
typedef __attribute__((ext_vector_type(4))) float f32x4;
typedef __attribute__((ext_vector_type(8))) u16 u16x8;

#define DEV __device__ __forceinline__

DEV u16 f2bf(float f) {
  u32 x = __float_as_uint(f);
  return (u16)((x + 0x7fffu + ((x >> 16) & 1u)) >> 16);  // RNE
}

// Problem dims: B=8 S=512 H=768 E=8 F=3072 K=2. fp32 I/O; internal bf16 MFMA.

// ---------- convert hidden fp32->bf16 + accumulate per-(b,h) pooled sums ----------
__global__ void convert_pool_kernel(const float* __restrict__ hidden, u16* __restrict__ hbf,
                                    float* __restrict__ pooled) {
  __shared__ float lp[768];
  const int b = blockIdx.y, chunk = blockIdx.x, tid = threadIdx.x;
  for (int h = tid; h < 768; h += 256) lp[h] = 0.f;
  __syncthreads();
  const size_t base = (size_t)b * 512 * 768 + (size_t)chunk * 32 * 768;
#pragma unroll
  for (int i = 0; i < 24; ++i) {
    const int idx = i * 256 + tid;              // float4 index within 32x768 chunk
    const float4 v = *(const float4*)(hidden + base + (size_t)idx * 4);
    u16* d = hbf + base + (size_t)idx * 4;
    d[0] = f2bf(v.x); d[1] = f2bf(v.y); d[2] = f2bf(v.z); d[3] = f2bf(v.w);
    const int h = (idx % 192) * 4;              // 768/4 = 192 float4 per row
    atomicAdd(&lp[h + 0], v.x); atomicAdd(&lp[h + 1], v.y);
    atomicAdd(&lp[h + 2], v.z); atomicAdd(&lp[h + 3], v.w);
  }
  __syncthreads();
  for (int h = tid; h < 768; h += 256) atomicAdd(&pooled[b * 768 + h], lp[h]);
}

// ---------- router finalize: logits = pooled@Wg/512, softmax, top2 ----------
__global__ void router_final_kernel(const float* __restrict__ pooled, const float* __restrict__ Wg,
                                    float* __restrict__ logits_out, int* __restrict__ sel,
                                    float* __restrict__ wsel) {
  __shared__ float l8[64];
  const int tid = threadIdx.x;
  const int b = tid >> 5, r = tid & 31, e = r >> 2, q = r & 3;
  float p = 0.f;
  for (int h = q * 192; h < q * 192 + 192; ++h) p += pooled[b * 768 + h] * Wg[h * 8 + e];
  p += __shfl_xor(p, 1);
  p += __shfl_xor(p, 2);
  if (q == 0) {
    const float lg = p * (1.f / 512.f);
    l8[b * 8 + e] = lg;
    logits_out[b * 8 + e] = lg;
  }
  __syncthreads();
  if (tid < 8) {
    const int bb = tid;
    float mx = -1e30f;
    for (int i = 0; i < 8; ++i) mx = fmaxf(mx, l8[bb * 8 + i]);
    float w[8], ssum = 0.f;
    for (int i = 0; i < 8; ++i) { w[i] = __expf(l8[bb * 8 + i] - mx); ssum += w[i]; }
    for (int i = 0; i < 8; ++i) w[i] /= ssum;
    int i0 = 0;
    for (int i = 1; i < 8; ++i) if (w[i] > w[i0]) i0 = i;   // first-occurrence ties (jax top_k)
    int i1 = (i0 == 0) ? 1 : 0;
    for (int i = 0; i < 8; ++i) if (i != i0 && w[i] > w[i1]) i1 = i;
    sel[bb * 2 + 0] = i0; sel[bb * 2 + 1] = i1;
    wsel[bb * 2 + 0] = w[i0]; wsel[bb * 2 + 1] = w[i1];
  }
}

// ---------- 64x64 tiled transpose, fp32 src -> bf16 dst ----------
__global__ void transpose_kernel(const float* __restrict__ src, u16* __restrict__ dst,
                                 int R, int C) {
  __shared__ u16 tile[64][72];
  const int e = blockIdx.z;
  src += (size_t)e * (size_t)R * C;
  dst += (size_t)e * (size_t)R * C;
  const int r0 = blockIdx.y * 64, c0 = blockIdx.x * 64;
  const int tid = threadIdx.x;
#pragma unroll
  for (int i = 0; i < 4; ++i) {
    const int ch = i * 256 + tid;
    const int row = ch >> 4, c4 = (ch & 15) * 4;
    const float4 v = *(const float4*)(src + (size_t)(r0 + row) * C + c0 + c4);
    tile[row][c4 + 0] = f2bf(v.x); tile[row][c4 + 1] = f2bf(v.y);
    tile[row][c4 + 2] = f2bf(v.z); tile[row][c4 + 3] = f2bf(v.w);
  }
  __syncthreads();
#pragma unroll
  for (int i = 0; i < 2; ++i) {
    const int ch = i * 256 + tid;
    const int drow = ch >> 3, r8 = (ch & 7) * 8;
    u16x8 v;
#pragma unroll
    for (int j = 0; j < 8; ++j) v[j] = tile[r8 + j][drow];
    *(u16x8*)(dst + (size_t)(c0 + drow) * R + r0 + r8) = v;
  }
}

// ---------- GEMM core (m97 structure): 128x128 tile, BK=64, 16x16x32 bf16 ----------
DEV void stage_tile(const u16* __restrict__ gbase, int ld, int row0, int k0,
                    u16* lds, int tid) {
  const int crow = tid >> 3;
  const int ccol = (tid & 7) * 8;
  const int wbase = tid & ~63;
#pragma unroll
  for (int i = 0; i < 4; ++i) {
    const u16* g = gbase + (size_t)(row0 + i * 32 + crow) * ld + k0 + ccol;
    u16* l = lds + (size_t)(i * 256 + wbase) * 8;
    __builtin_amdgcn_global_load_lds((const __attribute__((address_space(1))) void*)g,
                                     (__attribute__((address_space(3))) void*)l, 16, 0, 0);
  }
}

DEV void mfma_step(const u16* As, const u16* Bs, int wm, int wn, int mi, int kq,
                   f32x4 acc[4][4]) {
#pragma unroll
  for (int s2 = 0; s2 < 64; s2 += 32) {
    bf16x8 af[4], bfr[4];
#pragma unroll
    for (int mt = 0; mt < 4; ++mt)
      af[mt] = *(const bf16x8*)(As + (wm + mt * 16 + mi) * 64 + s2 + kq * 8);
#pragma unroll
    for (int nt = 0; nt < 4; ++nt)
      bfr[nt] = *(const bf16x8*)(Bs + (wn + nt * 16 + mi) * 64 + s2 + kq * 8);
#pragma unroll
    for (int mt = 0; mt < 4; ++mt)
#pragma unroll
      for (int nt = 0; nt < 4; ++nt)
        acc[mt][nt] = __builtin_amdgcn_mfma_f32_16x16x32_bf16(af[mt], bfr[nt], acc[mt][nt], 0, 0, 0);
  }
}

// ---------- GEMM1: hbuf = wgt * gelu(hbf @ W1[e] + b1[e]), bf16 out ----------
__global__ void gemm1_kernel(const u16* __restrict__ hbf, const u16* __restrict__ w1t,
                             const float* __restrict__ b1, u16* __restrict__ hbuf,
                             const int* __restrict__ sel, const float* __restrict__ wsel) {
  __shared__ __align__(16) u16 As[128 * 64];
  __shared__ __align__(16) u16 Bs[128 * 64];
  const int p = blockIdx.z;
  const int b = p >> 1;
  const int e = sel[p];
  const float wgt = wsel[p];
  const u16* A = hbf + (size_t)b * 512 * 768;
  const u16* Bt = w1t + (size_t)e * 3072 * 768;
  const int m0 = blockIdx.y * 128, n0 = blockIdx.x * 128;
  const int tid = threadIdx.x, lane = tid & 63;
  const int wv = tid >> 6;
  const int wm = (wv >> 1) * 64, wn = (wv & 1) * 64;
  const int mi = lane & 15, kq = lane >> 4;

  f32x4 acc[4][4] = {};
  for (int k0 = 0; k0 < 768; k0 += 64) {
    __syncthreads();
    stage_tile(A, 768, m0, k0, As, tid);
    stage_tile(Bt, 768, n0, k0, Bs, tid);
    __syncthreads();
    mfma_step(As, Bs, wm, wn, mi, kq, acc);
  }

  const float* b1e = b1 + e * 3072;
  u16* C = hbuf + (size_t)p * 512 * 3072;
#pragma unroll
  for (int nt = 0; nt < 4; ++nt) {
    const int col = n0 + wn + nt * 16 + mi;
    const float bias = b1e[col];
#pragma unroll
    for (int mt = 0; mt < 4; ++mt) {
#pragma unroll
      for (int r = 0; r < 4; ++r) {
        const int row = m0 + wm + mt * 16 + kq * 4 + r;  // C/D: col=lane&15, row=quad*4+reg
        const float x = acc[mt][nt][r] + bias;
        const float g = 0.5f * x * (1.f + erff(x * 0.70710678118654752f));  // exact GELU
        C[(size_t)row * 3072 + col] = f2bf(wgt * g);
      }
    }
  }
}

// ---------- init d_out with weighted bias (d_out is poisoned before every call) ----------
// grid (384, 8): per b, 512*768 floats = 98304 float4
__global__ void init_out_kernel(const float* __restrict__ b2, float* __restrict__ out,
                                const int* __restrict__ sel, const float* __restrict__ wsel) {
  const int b = blockIdx.y;
  const int e0 = sel[b * 2 + 0], e1 = sel[b * 2 + 1];
  const float w0 = wsel[b * 2 + 0], w1 = wsel[b * 2 + 1];
  const int idx = blockIdx.x * 256 + threadIdx.x;   // float4 index in [0, 98304)
  const int h = (idx % 192) * 4;
  const float4 v0 = *(const float4*)(b2 + e0 * 768 + h);
  const float4 v1 = *(const float4*)(b2 + e1 * 768 + h);
  float4 r;
  r.x = w0 * v0.x + w1 * v1.x; r.y = w0 * v0.y + w1 * v1.y;
  r.z = w0 * v0.z + w1 * v1.z; r.w = w0 * v0.w + w1 * v1.w;
  *(float4*)(out + (size_t)b * 512 * 768 + (size_t)idx * 4) = r;
}

// ---------- GEMM2 split-K: out[b] += hbuf_k @ W2[e_k] (fp32 atomics) ----------
// grid (6 ntiles, 4 mtiles, 32 = 8 b x 4 ksplits); each split = 24 BK64 steps
__global__ void gemm2_kernel(const u16* __restrict__ hbuf, const u16* __restrict__ w2t,
                             float* __restrict__ out,
                             const int* __restrict__ sel) {
  __shared__ __align__(16) u16 As[128 * 64];
  __shared__ __align__(16) u16 Bs[128 * 64];
  const int z = blockIdx.z;
  const int b = z >> 2, ks = z & 3;
  const int kslot = ks >> 1;                        // which of the 2 experts
  const int e = sel[b * 2 + kslot];
  const u16* A = hbuf + (size_t)(b * 2 + kslot) * 512 * 3072;
  const u16* Bt = w2t + (size_t)e * 768 * 3072;
  const int kbase = (ks & 1) * 1536;                // half of the expert's K=3072
  const int m0 = blockIdx.y * 128, n0 = blockIdx.x * 128;
  const int tid = threadIdx.x, lane = tid & 63;
  const int wv = tid >> 6;
  const int wm = (wv >> 1) * 64, wn = (wv & 1) * 64;
  const int mi = lane & 15, kq = lane >> 4;

  f32x4 acc[4][4] = {};
  for (int t = 0; t < 24; ++t) {
    const int k0 = kbase + t * 64;
    __syncthreads();
    stage_tile(A, 3072, m0, k0, As, tid);
    stage_tile(Bt, 3072, n0, k0, Bs, tid);
    __syncthreads();
    mfma_step(As, Bs, wm, wn, mi, kq, acc);
  }

  float* C = out + (size_t)b * 512 * 768;
#pragma unroll
  for (int nt = 0; nt < 4; ++nt) {
    const int col = n0 + wn + nt * 16 + mi;
#pragma unroll
    for (int mt = 0; mt < 4; ++mt) {
#pragma unroll
      for (int r = 0; r < 4; ++r) {
        const int row = m0 + wm + mt * 16 + kq * 4 + r;
        atomicAdd(&C[(size_t)row * 768 + col], acc[mt][nt][r]);
      }
    }
  }
}

extern "C" void kernel_launch(void* const* d_in, const int* in_sizes, int n_in,
                              void* d_out, int out_size, void* d_ws, size_t ws_size,
                              hipStream_t stream) {
  const float* hidden = (const float*)d_in[0];  // [8,512,768] fp32
  const float* Wg     = (const float*)d_in[1];  // [768,8]
  const float* W1     = (const float*)d_in[2];  // [8,768,3072]
  const float* b1     = (const float*)d_in[3];  // [8,3072]
  const float* W2     = (const float*)d_in[4];  // [8,3072,768]
  const float* b2     = (const float*)d_in[5];  // [8,768]
  float* out = (float*)d_out;                   // [8,512,768] ++ logits [8,8], fp32

  char* ws = (char*)d_ws;
  int*   sel    = (int*)ws;                     // [16]
  float* wsel   = (float*)(ws + 64);            // [16]
  float* pooled = (float*)(ws + 128);           // [8][768] fp32 (zeroed below)
  u16* hbf  = (u16*)(ws + 32768);               // [8][512][768] bf16
  u16* wT   = hbf + (size_t)8 * 512 * 768;      // [8][3072][768] bf16 (w1t, then w2t)
  u16* hbuf = wT + (size_t)8 * 3072 * 768;      // [16][512][3072] bf16

  float* logits_out = out + (size_t)8 * 512 * 768;

  hipMemsetAsync(ws, 0, 32768, stream);  // zero sel/wsel/pooled
  convert_pool_kernel<<<dim3(16, 8), 256, 0, stream>>>(hidden, hbf, pooled);
  router_final_kernel<<<1, 256, 0, stream>>>(pooled, Wg, logits_out, sel, wsel);
  transpose_kernel<<<dim3(48, 12, 8), 256, 0, stream>>>(W1, wT, 768, 3072);   // [H,F]->[F,H]
  gemm1_kernel<<<dim3(24, 4, 16), 256, 0, stream>>>(hbf, wT, b1, hbuf, sel, wsel);
  transpose_kernel<<<dim3(12, 48, 8), 256, 0, stream>>>(W2, wT, 3072, 768);   // [F,H]->[H,F]
  init_out_kernel<<<dim3(384, 8), 256, 0, stream>>>(b2, out, sel, wsel);
  gemm2_kernel<<<dim3(6, 4, 32), 256, 0, stream>>>(hbuf, wT, out, sel);
}